// Round 1
// baseline (1504.845 us; speedup 1.0000x reference)
//
#include <hip/hip_runtime.h>

#define BB 512
#define TT 1024
#define II 50
#define HH 32

__device__ __forceinline__ float fast_rcp(float x) { return __builtin_amdgcn_rcpf(x); }
__device__ __forceinline__ float sigm(float x) { return fast_rcp(1.f + __expf(-x)); }
__device__ __forceinline__ float tanh_(float x) {
    // tanh(x) = 1 - 2/(exp(2x)+1); saturates correctly at +/-inf
    return 1.f - 2.f * fast_rcp(1.f + __expf(2.f * x));
}

// d_out is poisoned before every launch: initialize every element to the
// combined FC bias b_comb = fc3_w @ fc1_b + fc3_b. The scan kernels then
// atomicAdd their direction's partial dot on top.
__global__ void init_out_kernel(float* __restrict__ out,
                                const float* __restrict__ fc1_b,
                                const float* __restrict__ fc3_w,
                                const float* __restrict__ fc3_b,
                                int n) {
    int idx = blockIdx.x * blockDim.x + threadIdx.x;
    float b = fc3_b[0];
    #pragma unroll
    for (int k = 0; k < 64; ++k) b += fc3_w[k] * fc1_b[k];
    if (idx < n) out[idx] = b;
}

// One wave (64 threads) per (batch, direction) sequence.
// Lane k owns gate rows k and 64+k of the (128, *) weight matrices:
//   lanes 0..31  -> (i_k, g_k)
//   lanes 32..63 -> (f_{k-32}, o_{k-32})
__global__ void __launch_bounds__(64, 1) lstm_scan_kernel(
    const float* __restrict__ x,
    const float* __restrict__ w_ih_f, const float* __restrict__ w_hh_f,
    const float* __restrict__ b_ih_f, const float* __restrict__ b_hh_f,
    const float* __restrict__ w_ih_r, const float* __restrict__ w_hh_r,
    const float* __restrict__ b_ih_r, const float* __restrict__ b_hh_r,
    const float* __restrict__ fc1_w, const float* __restrict__ fc3_w,
    float* __restrict__ out)
{
    const int lane = threadIdx.x;          // 0..63
    const int b    = blockIdx.x >> 1;
    const int dir  = blockIdx.x & 1;

    const float* w_ih = dir ? w_ih_r : w_ih_f;
    const float* w_hh = dir ? w_hh_r : w_hh_f;
    const float* b_ih = dir ? b_ih_r : b_ih_f;
    const float* b_hh = dir ? b_hh_r : b_hh_f;

    const int r1 = lane;        // gate row 1 (i or f)
    const int r2 = 64 + lane;   // gate row 2 (g or o)

    // Weights resident in VGPRs: 2*(50+32) = 164 per lane.
    float wih1[II], wih2[II], whh1[HH], whh2[HH];
    #pragma unroll
    for (int m = 0; m < II; ++m) { wih1[m] = w_ih[r1 * II + m]; wih2[m] = w_ih[r2 * II + m]; }
    #pragma unroll
    for (int m = 0; m < HH; ++m) { whh1[m] = w_hh[r1 * HH + m]; whh2[m] = w_hh[r2 * HH + m]; }
    const float bb1 = b_ih[r1] + b_hh[r1];
    const float bb2 = b_ih[r2] + b_hh[r2];

    // Fused FC head: w_comb[j] = sum_n fc3_w[n] * fc1_w[n][j].
    // This lane's hidden unit (lanes 0..31) maps to j = dir*32 + (lane&31).
    float wc = 0.f;
    {
        const int j = dir * HH + (lane & 31);
        #pragma unroll
        for (int n = 0; n < 64; ++n) wc += fc3_w[n] * fc1_w[n * 64 + j];
    }

    float hs[HH];
    #pragma unroll
    for (int m = 0; m < HH; ++m) hs[m] = 0.f;
    float c = 0.f;

    const float* xb   = x + (size_t)b * TT * II;
    float*       outb = out + (size_t)b * TT;

    for (int s = 0; s < TT; ++s) {
        const int tt = dir ? (TT - 1 - s) : s;
        const float* xr = xb + tt * II;   // wave-uniform address -> scalar loads

        float z1 = bb1, z2 = bb2;
        #pragma unroll
        for (int m = 0; m < II; ++m) {
            const float xv = xr[m];
            z1 += xv * wih1[m];
            z2 += xv * wih2[m];
        }
        #pragma unroll
        for (int m = 0; m < HH; ++m) {
            z1 += hs[m] * whh1[m];
            z2 += hs[m] * whh2[m];
        }

        // lanes<32: a1=sig(i), a2=tanh(g); lanes>=32: a1=sig(f), a2=sig(o)
        const float a1 = sigm(z1);
        const float a2 = (lane < HH) ? tanh_(z2) : sigm(z2);
        const float p  = a1 * a2;                 // lanes<32: sig(i)*tanh(g)

        const float fhat = __shfl_xor(a1, 32);    // lanes<32 receive sig(f)
        const float ohat = __shfl_xor(a2, 32);    // lanes<32 receive sig(o)

        // Valid in lanes 0..31; lanes>=32 compute bounded garbage (unused).
        c = fhat * c + p;
        const float h = ohat * tanh_(c);

        // Fused FC partial: sum_k h[k] * wc[k]  (this direction's 32 units)
        float d = (lane < HH) ? h * wc : 0.f;
        #pragma unroll
        for (int off = 32; off >= 1; off >>= 1) d += __shfl_xor(d, off);
        if (lane == 0) atomicAdd(&outb[tt], d);

        // Broadcast h (lanes 0..31) into wave-uniform registers for next step.
        #pragma unroll
        for (int m = 0; m < HH; ++m) {
            const int hi = __builtin_amdgcn_readlane(__float_as_int(h), m);
            hs[m] = __int_as_float(hi);
        }
    }
}

extern "C" void kernel_launch(void* const* d_in, const int* in_sizes, int n_in,
                              void* d_out, int out_size, void* d_ws, size_t ws_size,
                              hipStream_t stream) {
    const float* x      = (const float*)d_in[0];
    const float* w_ih_f = (const float*)d_in[1];
    const float* w_hh_f = (const float*)d_in[2];
    const float* b_ih_f = (const float*)d_in[3];
    const float* b_hh_f = (const float*)d_in[4];
    const float* w_ih_r = (const float*)d_in[5];
    const float* w_hh_r = (const float*)d_in[6];
    const float* b_ih_r = (const float*)d_in[7];
    const float* b_hh_r = (const float*)d_in[8];
    const float* fc1_w  = (const float*)d_in[9];
    const float* fc1_b  = (const float*)d_in[10];
    const float* fc3_w  = (const float*)d_in[11];
    const float* fc3_b  = (const float*)d_in[12];
    float* out = (float*)d_out;

    const int n = BB * TT;  // 524288 outputs
    init_out_kernel<<<(n + 255) / 256, 256, 0, stream>>>(out, fc1_b, fc3_w, fc3_b, n);

    // 1024 blocks = (batch, direction) pairs; one wave each.
    lstm_scan_kernel<<<BB * 2, 64, 0, stream>>>(
        x, w_ih_f, w_hh_f, b_ih_f, b_hh_f,
        w_ih_r, w_hh_r, b_ih_r, b_hh_r,
        fc1_w, fc3_w, out);
}

// Round 2
// 977.227 us; speedup vs baseline: 1.5399x; 1.5399x over previous
//
#include <hip/hip_runtime.h>

#define BB 512
#define TT 1024
#define II 50
#define HH 32

__device__ __forceinline__ float fast_rcp(float x) { return __builtin_amdgcn_rcpf(x); }
__device__ __forceinline__ float sigm(float x) { return fast_rcp(1.f + __expf(-x)); }
__device__ __forceinline__ float tanh_(float x) {
    // tanh(x) = 1 - 2/(exp(2x)+1); saturates correctly at +/-inf
    return 1.f - 2.f * fast_rcp(1.f + __expf(2.f * x));
}

// d_out is poisoned before every launch: initialize every element to the
// combined FC bias b_comb = fc3_w @ fc1_b + fc3_b. The scan kernel then
// atomicAdds each direction's partial dot on top.
__global__ void init_out_kernel(float* __restrict__ out,
                                const float* __restrict__ fc1_b,
                                const float* __restrict__ fc3_w,
                                const float* __restrict__ fc3_b,
                                int n) {
    int idx = blockIdx.x * blockDim.x + threadIdx.x;
    float b = fc3_b[0];
    #pragma unroll
    for (int k = 0; k < 64; ++k) b += fc3_w[k] * fc1_b[k];
    if (idx < n) out[idx] = b;
}

// 2x input-projection rows per lane, 4-way split accumulators (breaks the
// serial FMA chain the compiler otherwise emits without fast-math).
__device__ __forceinline__ void xproj(const float (&xa)[II],
                                      const float (&w1)[II], const float (&w2)[II],
                                      float bb1, float bb2, float& o1, float& o2)
{
    float a0 = 0.f, a1 = 0.f, a2 = 0.f, a3 = 0.f;
    float c0 = 0.f, c1 = 0.f, c2 = 0.f, c3 = 0.f;
    #pragma unroll
    for (int m = 0; m < 48; m += 4) {
        a0 = fmaf(xa[m    ], w1[m    ], a0); c0 = fmaf(xa[m    ], w2[m    ], c0);
        a1 = fmaf(xa[m + 1], w1[m + 1], a1); c1 = fmaf(xa[m + 1], w2[m + 1], c1);
        a2 = fmaf(xa[m + 2], w1[m + 2], a2); c2 = fmaf(xa[m + 2], w2[m + 2], c2);
        a3 = fmaf(xa[m + 3], w1[m + 3], a3); c3 = fmaf(xa[m + 3], w2[m + 3], c3);
    }
    a0 = fmaf(xa[48], w1[48], a0); a1 = fmaf(xa[49], w1[49], a1);
    c0 = fmaf(xa[48], w2[48], c0); c1 = fmaf(xa[49], w2[49], c1);
    o1 = ((a0 + a1) + (a2 + a3)) + bb1;
    o2 = ((c0 + c1) + (c2 + c3)) + bb2;
}

// One wave (64 threads) per (batch, direction) sequence.
// Lane k owns gate rows k and 64+k of the (128, *) weight matrices:
//   lanes 0..31  -> (i_k, g_k)     lanes 32..63 -> (f_{k-32}, o_{k-32})
__global__ void __launch_bounds__(64, 1) lstm_scan_kernel(
    const float* __restrict__ x,
    const float* __restrict__ w_ih_f, const float* __restrict__ w_hh_f,
    const float* __restrict__ b_ih_f, const float* __restrict__ b_hh_f,
    const float* __restrict__ w_ih_r, const float* __restrict__ w_hh_r,
    const float* __restrict__ b_ih_r, const float* __restrict__ b_hh_r,
    const float* __restrict__ fc1_w, const float* __restrict__ fc3_w,
    float* __restrict__ out)
{
    const int lane = threadIdx.x;          // 0..63
    const int b    = blockIdx.x >> 1;
    const int dir  = blockIdx.x & 1;

    const float* w_ih = dir ? w_ih_r : w_ih_f;
    const float* w_hh = dir ? w_hh_r : w_hh_f;
    const float* b_ih = dir ? b_ih_r : b_ih_f;
    const float* b_hh = dir ? b_hh_r : b_hh_f;

    const int r1 = lane;        // gate row 1 (i or f)
    const int r2 = 64 + lane;   // gate row 2 (g or o)

    // Weights resident in VGPRs: 2*(50+32) = 164 per lane.
    float wih1[II], wih2[II], whh1[HH], whh2[HH];
    #pragma unroll
    for (int m = 0; m < II; ++m) { wih1[m] = w_ih[r1 * II + m]; wih2[m] = w_ih[r2 * II + m]; }
    #pragma unroll
    for (int m = 0; m < HH; ++m) { whh1[m] = w_hh[r1 * HH + m]; whh2[m] = w_hh[r2 * HH + m]; }
    const float bb1 = b_ih[r1] + b_hh[r1];
    const float bb2 = b_ih[r2] + b_hh[r2];

    // Single-sigmoid activation: a2 = A2*sigm(M2*z2) + B2
    //   lanes<32 (g-gate): tanh(z) = 2*sigm(2z)-1  -> M2=2, A2=2, B2=-1
    //   lanes>=32 (o-gate): sigm(z)                -> M2=1, A2=1, B2=0
    const float M2 = (lane < HH) ? 2.f : 1.f;
    const float A2 = M2;
    const float B2 = (lane < HH) ? -1.f : 0.f;

    // Fused FC head: w_comb[j] = sum_n fc3_w[n] * fc1_w[n][j].
    // This lane's hidden unit (lanes 0..31) maps to j = dir*32 + (lane&31).
    float wc = 0.f;
    {
        const int j = dir * HH + (lane & 31);
        #pragma unroll
        for (int n = 0; n < 64; ++n) wc += fc3_w[n] * fc1_w[n * 64 + j];
    }

    // Deferred FC buffer: hbuf[k][t'] (transposed), stride 65 so per-step
    // writes (32 lanes, bank (k+t')%32) and flush reads (64 lanes, bank
    // (k+L)%32, 2-way) are conflict-free.
    __shared__ float hbuf[HH][65];

    float hs[HH];
    #pragma unroll
    for (int m = 0; m < HH; ++m) hs[m] = 0.f;
    float c = 0.f;

    const float* xb   = x + (size_t)b * TT * II;
    float*       outb = out + (size_t)b * TT;

    // Prologue: load row for s=0 and compute its projection.
    float xz1, xz2;
    {
        const int t0 = dir ? (TT - 1) : 0;
        const float* xr = xb + (size_t)t0 * II;
        float x0[II];
        #pragma unroll
        for (int m = 0; m < II; ++m) x0[m] = xr[m];
        xproj(x0, wih1, wih2, bb1, bb2, xz1, xz2);
    }

    for (int s = 0; s < TT; ++s) {
        // ---- issue next row's loads early (off the recurrence chain) ----
        const int sn = (s + 1 < TT) ? (s + 1) : s;
        const int tn = dir ? (TT - 1 - sn) : sn;
        const float* xrn = xb + (size_t)tn * II;
        float xn[II];
        #pragma unroll
        for (int m = 0; m < II; ++m) xn[m] = xrn[m];

        // ---- recurrence chain: z = xz + h @ whh ----
        float h0 = 0.f, h1 = 0.f, h2 = 0.f, h3 = 0.f;
        float g0 = 0.f, g1 = 0.f, g2 = 0.f, g3 = 0.f;
        #pragma unroll
        for (int m = 0; m < HH; m += 4) {
            h0 = fmaf(hs[m    ], whh1[m    ], h0); g0 = fmaf(hs[m    ], whh2[m    ], g0);
            h1 = fmaf(hs[m + 1], whh1[m + 1], h1); g1 = fmaf(hs[m + 1], whh2[m + 1], g1);
            h2 = fmaf(hs[m + 2], whh1[m + 2], h2); g2 = fmaf(hs[m + 2], whh2[m + 2], g2);
            h3 = fmaf(hs[m + 3], whh1[m + 3], h3); g3 = fmaf(hs[m + 3], whh2[m + 3], g3);
        }
        const float z1 = xz1 + ((h0 + h1) + (h2 + h3));
        const float z2 = xz2 + ((g0 + g1) + (g2 + g3));

        // lanes<32: a1=sig(i), a2=tanh(g); lanes>=32: a1=sig(f), a2=sig(o)
        const float a1 = sigm(z1);
        const float a2 = fmaf(A2, sigm(M2 * z2), B2);
        const float p  = a1 * a2;

        const float fhat = __shfl_xor(a1, 32);    // lanes<32 receive sig(f)
        const float ohat = __shfl_xor(a2, 32);    // lanes<32 receive sig(o)

        c = fmaf(fhat, c, p);                     // valid in lanes 0..31
        const float h = ohat * tanh_(c);

        // Deferred FC: one LDS write per step (off-chain).
        if (lane < HH) hbuf[lane][s & 63] = h * wc;

        // Broadcast h (lanes 0..31) into wave-uniform registers.
        #pragma unroll
        for (int m = 0; m < HH; ++m)
            hs[m] = __int_as_float(__builtin_amdgcn_readlane(__float_as_int(h), m));

        // ---- pipelined input projection for step s+1 (off-chain) ----
        xproj(xn, wih1, wih2, bb1, bb2, xz1, xz2);

        // ---- flush FC partials every 64 steps ----
        if ((s & 63) == 63) {
            const int sbase = s - 63;
            float d0 = 0.f, d1 = 0.f, d2 = 0.f, d3 = 0.f;
            #pragma unroll
            for (int k = 0; k < HH; k += 4) {
                d0 += hbuf[k    ][lane];
                d1 += hbuf[k + 1][lane];
                d2 += hbuf[k + 2][lane];
                d3 += hbuf[k + 3][lane];
            }
            const float d = (d0 + d1) + (d2 + d3);
            const int t = dir ? (TT - 1 - sbase - lane) : (sbase + lane);
            atomicAdd(&outb[t], d);
        }
    }
}

extern "C" void kernel_launch(void* const* d_in, const int* in_sizes, int n_in,
                              void* d_out, int out_size, void* d_ws, size_t ws_size,
                              hipStream_t stream) {
    const float* x      = (const float*)d_in[0];
    const float* w_ih_f = (const float*)d_in[1];
    const float* w_hh_f = (const float*)d_in[2];
    const float* b_ih_f = (const float*)d_in[3];
    const float* b_hh_f = (const float*)d_in[4];
    const float* w_ih_r = (const float*)d_in[5];
    const float* w_hh_r = (const float*)d_in[6];
    const float* b_ih_r = (const float*)d_in[7];
    const float* b_hh_r = (const float*)d_in[8];
    const float* fc1_w  = (const float*)d_in[9];
    const float* fc1_b  = (const float*)d_in[10];
    const float* fc3_w  = (const float*)d_in[11];
    const float* fc3_b  = (const float*)d_in[12];
    float* out = (float*)d_out;

    const int n = BB * TT;  // 524288 outputs
    init_out_kernel<<<(n + 255) / 256, 256, 0, stream>>>(out, fc1_b, fc3_w, fc3_b, n);

    // 1024 blocks = (batch, direction) pairs; one wave each.
    lstm_scan_kernel<<<BB * 2, 64, 0, stream>>>(
        x, w_ih_f, w_hh_f, b_ih_f, b_hh_f,
        w_ih_r, w_hh_r, b_ih_r, b_hh_r,
        fc1_w, fc3_w, out);
}

// Round 3
// 976.764 us; speedup vs baseline: 1.5406x; 1.0005x over previous
//
#include <hip/hip_runtime.h>

#define BB 512
#define TT 1024
#define II 50
#define HH 32
// P: [dir][b][q][128] fp32, gate-pair interleaved (pos 2k = gate k, 2k+1 = gate 64+k)
#define P_BYTES ((size_t)2 * BB * TT * 128 * 4)

__device__ __forceinline__ float fast_rcp(float x) { return __builtin_amdgcn_rcpf(x); }
__device__ __forceinline__ float sigm(float x) { return fast_rcp(1.f + __expf(-x)); }
__device__ __forceinline__ float tanh_(float x) {
    return 1.f - 2.f * fast_rcp(1.f + __expf(2.f * x));
}

// d_out is poisoned before every launch: initialize to combined FC bias
// b_comb = fc3_w @ fc1_b + fc3_b; scan kernels atomicAdd partial dots on top.
__global__ void init_out_kernel(float* __restrict__ out,
                                const float* __restrict__ fc1_b,
                                const float* __restrict__ fc3_w,
                                const float* __restrict__ fc3_b,
                                int n) {
    int idx = blockIdx.x * blockDim.x + threadIdx.x;
    float b = fc3_b[0];
    #pragma unroll
    for (int k = 0; k < 64; ++k) b += fc3_w[k] * fc1_b[k];
    if (idx < n) out[idx] = b;
}

__device__ __forceinline__ float dot50(const float* __restrict__ w,
                                       const float (&xv)[II]) {
    float a0 = 0.f, a1 = 0.f, a2 = 0.f, a3 = 0.f;
    #pragma unroll
    for (int m = 0; m < 48; m += 4) {
        a0 = fmaf(xv[m    ], w[m    ], a0);
        a1 = fmaf(xv[m + 1], w[m + 1], a1);
        a2 = fmaf(xv[m + 2], w[m + 2], a2);
        a3 = fmaf(xv[m + 3], w[m + 3], a3);
    }
    a0 = fmaf(xv[48], w[48], a0);
    a1 = fmaf(xv[49], w[49], a1);
    return (a0 + a1) + (a2 + a3);
}

// Input projection GEMM: P[dir][b][q][128] = x[b][t] @ w_ih^T + (b_ih+b_hh),
// q = scan-order step (reversed for dir=1). Weights in LDS (broadcast reads).
// One thread per (b,t) row; lane->consecutive t => coalesced x reads and
// dense P writes (each lane streams its own 512B row via float4 stores).
__global__ void __launch_bounds__(256) proj_kernel(
    const float* __restrict__ x,
    const float* __restrict__ w_ih_f, const float* __restrict__ b_ih_f,
    const float* __restrict__ b_hh_f,
    const float* __restrict__ w_ih_r, const float* __restrict__ b_ih_r,
    const float* __restrict__ b_hh_r,
    float* __restrict__ P)
{
    const int dir = blockIdx.y;
    const float* w_ih = dir ? w_ih_r : w_ih_f;
    const float* bi   = dir ? b_ih_r : b_ih_f;
    const float* bh   = dir ? b_hh_r : b_hh_f;

    __shared__ float wsm[128 * II];
    __shared__ float bsm[128];
    const int tid = threadIdx.x;
    for (int i = tid; i < 128 * II; i += 256) wsm[i] = w_ih[i];
    if (tid < 128) bsm[tid] = bi[tid] + bh[tid];
    __syncthreads();

    const int r = blockIdx.x * 256 + tid;       // 0 .. B*T-1
    const int b = r >> 10;
    const int t = r & (TT - 1);
    const float* xr = x + (size_t)r * II;
    float xv[II];
    #pragma unroll
    for (int m = 0; m < II; ++m) xv[m] = xr[m];

    const int q = dir ? (TT - 1 - t) : t;
    float* Pr = P + ((size_t)(dir * BB + b) * TT + q) * 128;

    for (int k = 0; k < 64; k += 2) {           // k even => 16B-aligned store
        float4 z;
        z.x = dot50(&wsm[(k     ) * II], xv) + bsm[k];
        z.y = dot50(&wsm[(64 + k) * II], xv) + bsm[64 + k];
        z.z = dot50(&wsm[(k +  1) * II], xv) + bsm[k + 1];
        z.w = dot50(&wsm[(65 + k) * II], xv) + bsm[65 + k];
        *(float4*)(Pr + 2 * k) = z;
    }
}

// Recurrence-only scan: one wave per (b,dir). Lane k owns gate rows k, 64+k.
// Per step: prefetched float2 gate-pair (ring depth 4), 64-FMA hh dot,
// activations, cross-half shuffle, readlane broadcast, deferred FC.
__global__ void __launch_bounds__(64, 1) lstm_scan_split(
    const float* __restrict__ P,
    const float* __restrict__ w_hh_f, const float* __restrict__ w_hh_r,
    const float* __restrict__ fc1_w, const float* __restrict__ fc3_w,
    float* __restrict__ out)
{
    const int lane = threadIdx.x;
    const int b    = blockIdx.x >> 1;
    const int dir  = blockIdx.x & 1;

    const float* w_hh = dir ? w_hh_r : w_hh_f;
    const int r1 = lane, r2 = 64 + lane;

    float whh1[HH], whh2[HH];
    #pragma unroll
    for (int m = 0; m < HH; ++m) { whh1[m] = w_hh[r1 * HH + m]; whh2[m] = w_hh[r2 * HH + m]; }

    // a2 = A2*sigm(M2*z2)+B2: lanes<32 tanh(g), lanes>=32 sigm(o)
    const float M2 = (lane < HH) ? 2.f : 1.f;
    const float A2 = M2;
    const float B2 = (lane < HH) ? -1.f : 0.f;

    float wc = 0.f;
    {
        const int j = dir * HH + (lane & 31);
        #pragma unroll
        for (int n = 0; n < 64; ++n) wc += fc3_w[n] * fc1_w[n * 64 + j];
    }

    __shared__ float hbuf[HH][65];

    float hs[HH];
    #pragma unroll
    for (int m = 0; m < HH; ++m) hs[m] = 0.f;
    float c = 0.f;

    const float2* Pb  = (const float2*)(P + ((size_t)(dir * BB + b) * TT) * 128) + lane;
    float*        outb = out + (size_t)b * TT;

    float2 pz[4];
    #pragma unroll
    for (int u = 0; u < 4; ++u) pz[u] = Pb[(size_t)u * 64];

    for (int s = 0; s < TT; s += 4) {
        #pragma unroll
        for (int u = 0; u < 4; ++u) {
            const int S = s + u;
            const float2 xz = pz[u];
            // refill ring (4 steps ahead, off-chain)
            const int qn = (S + 4 < TT) ? S + 4 : TT - 1;
            pz[u] = Pb[(size_t)qn * 64];

            float h0 = 0.f, h1 = 0.f, h2 = 0.f, h3 = 0.f;
            float g0 = 0.f, g1 = 0.f, g2 = 0.f, g3 = 0.f;
            #pragma unroll
            for (int m = 0; m < HH; m += 4) {
                h0 = fmaf(hs[m    ], whh1[m    ], h0); g0 = fmaf(hs[m    ], whh2[m    ], g0);
                h1 = fmaf(hs[m + 1], whh1[m + 1], h1); g1 = fmaf(hs[m + 1], whh2[m + 1], g1);
                h2 = fmaf(hs[m + 2], whh1[m + 2], h2); g2 = fmaf(hs[m + 2], whh2[m + 2], g2);
                h3 = fmaf(hs[m + 3], whh1[m + 3], h3); g3 = fmaf(hs[m + 3], whh2[m + 3], g3);
            }
            const float z1 = xz.x + ((h0 + h1) + (h2 + h3));
            const float z2 = xz.y + ((g0 + g1) + (g2 + g3));

            const float a1 = sigm(z1);
            const float a2 = fmaf(A2, sigm(M2 * z2), B2);
            const float p  = a1 * a2;

            const float fhat = __shfl_xor(a1, 32);
            const float ohat = __shfl_xor(a2, 32);

            c = fmaf(fhat, c, p);                 // valid lanes 0..31
            const float h = ohat * tanh_(c);

            if (lane < HH) hbuf[lane][S & 63] = h * wc;

            #pragma unroll
            for (int m = 0; m < HH; ++m)
                hs[m] = __int_as_float(__builtin_amdgcn_readlane(__float_as_int(h), m));

            if ((S & 63) == 63) {
                const int sbase = S - 63;
                float d0 = 0.f, d1 = 0.f, d2 = 0.f, d3 = 0.f;
                #pragma unroll
                for (int k = 0; k < HH; k += 4) {
                    d0 += hbuf[k    ][lane];
                    d1 += hbuf[k + 1][lane];
                    d2 += hbuf[k + 2][lane];
                    d3 += hbuf[k + 3][lane];
                }
                const float d = (d0 + d1) + (d2 + d3);
                const int t = dir ? (TT - 1 - sbase - lane) : (sbase + lane);
                atomicAdd(&outb[t], d);
            }
        }
    }
}

// ---------------- Fallback: round-2 fused kernel (used if ws too small) ----
__device__ __forceinline__ void xproj(const float (&xa)[II],
                                      const float (&w1)[II], const float (&w2)[II],
                                      float bb1, float bb2, float& o1, float& o2)
{
    float a0 = 0.f, a1 = 0.f, a2 = 0.f, a3 = 0.f;
    float c0 = 0.f, c1 = 0.f, c2 = 0.f, c3 = 0.f;
    #pragma unroll
    for (int m = 0; m < 48; m += 4) {
        a0 = fmaf(xa[m    ], w1[m    ], a0); c0 = fmaf(xa[m    ], w2[m    ], c0);
        a1 = fmaf(xa[m + 1], w1[m + 1], a1); c1 = fmaf(xa[m + 1], w2[m + 1], c1);
        a2 = fmaf(xa[m + 2], w1[m + 2], a2); c2 = fmaf(xa[m + 2], w2[m + 2], c2);
        a3 = fmaf(xa[m + 3], w1[m + 3], a3); c3 = fmaf(xa[m + 3], w2[m + 3], c3);
    }
    a0 = fmaf(xa[48], w1[48], a0); a1 = fmaf(xa[49], w1[49], a1);
    c0 = fmaf(xa[48], w2[48], c0); c1 = fmaf(xa[49], w2[49], c1);
    o1 = ((a0 + a1) + (a2 + a3)) + bb1;
    o2 = ((c0 + c1) + (c2 + c3)) + bb2;
}

__global__ void __launch_bounds__(64, 1) lstm_scan_fused(
    const float* __restrict__ x,
    const float* __restrict__ w_ih_f, const float* __restrict__ w_hh_f,
    const float* __restrict__ b_ih_f, const float* __restrict__ b_hh_f,
    const float* __restrict__ w_ih_r, const float* __restrict__ w_hh_r,
    const float* __restrict__ b_ih_r, const float* __restrict__ b_hh_r,
    const float* __restrict__ fc1_w, const float* __restrict__ fc3_w,
    float* __restrict__ out)
{
    const int lane = threadIdx.x;
    const int b    = blockIdx.x >> 1;
    const int dir  = blockIdx.x & 1;

    const float* w_ih = dir ? w_ih_r : w_ih_f;
    const float* w_hh = dir ? w_hh_r : w_hh_f;
    const float* b_ih = dir ? b_ih_r : b_ih_f;
    const float* b_hh = dir ? b_hh_r : b_hh_f;

    const int r1 = lane, r2 = 64 + lane;

    float wih1[II], wih2[II], whh1[HH], whh2[HH];
    #pragma unroll
    for (int m = 0; m < II; ++m) { wih1[m] = w_ih[r1 * II + m]; wih2[m] = w_ih[r2 * II + m]; }
    #pragma unroll
    for (int m = 0; m < HH; ++m) { whh1[m] = w_hh[r1 * HH + m]; whh2[m] = w_hh[r2 * HH + m]; }
    const float bb1 = b_ih[r1] + b_hh[r1];
    const float bb2 = b_ih[r2] + b_hh[r2];

    const float M2 = (lane < HH) ? 2.f : 1.f;
    const float A2 = M2;
    const float B2 = (lane < HH) ? -1.f : 0.f;

    float wc = 0.f;
    {
        const int j = dir * HH + (lane & 31);
        #pragma unroll
        for (int n = 0; n < 64; ++n) wc += fc3_w[n] * fc1_w[n * 64 + j];
    }

    __shared__ float hbuf[HH][65];

    float hs[HH];
    #pragma unroll
    for (int m = 0; m < HH; ++m) hs[m] = 0.f;
    float c = 0.f;

    const float* xb   = x + (size_t)b * TT * II;
    float*       outb = out + (size_t)b * TT;

    float xz1, xz2;
    {
        const int t0 = dir ? (TT - 1) : 0;
        const float* xr = xb + (size_t)t0 * II;
        float x0[II];
        #pragma unroll
        for (int m = 0; m < II; ++m) x0[m] = xr[m];
        xproj(x0, wih1, wih2, bb1, bb2, xz1, xz2);
    }

    for (int s = 0; s < TT; ++s) {
        const int sn = (s + 1 < TT) ? (s + 1) : s;
        const int tn = dir ? (TT - 1 - sn) : sn;
        const float* xrn = xb + (size_t)tn * II;
        float xn[II];
        #pragma unroll
        for (int m = 0; m < II; ++m) xn[m] = xrn[m];

        float h0 = 0.f, h1 = 0.f, h2 = 0.f, h3 = 0.f;
        float g0 = 0.f, g1 = 0.f, g2 = 0.f, g3 = 0.f;
        #pragma unroll
        for (int m = 0; m < HH; m += 4) {
            h0 = fmaf(hs[m    ], whh1[m    ], h0); g0 = fmaf(hs[m    ], whh2[m    ], g0);
            h1 = fmaf(hs[m + 1], whh1[m + 1], h1); g1 = fmaf(hs[m + 1], whh2[m + 1], g1);
            h2 = fmaf(hs[m + 2], whh1[m + 2], h2); g2 = fmaf(hs[m + 2], whh2[m + 2], g2);
            h3 = fmaf(hs[m + 3], whh1[m + 3], h3); g3 = fmaf(hs[m + 3], whh2[m + 3], g3);
        }
        const float z1 = xz1 + ((h0 + h1) + (h2 + h3));
        const float z2 = xz2 + ((g0 + g1) + (g2 + g3));

        const float a1 = sigm(z1);
        const float a2 = fmaf(A2, sigm(M2 * z2), B2);
        const float p  = a1 * a2;

        const float fhat = __shfl_xor(a1, 32);
        const float ohat = __shfl_xor(a2, 32);

        c = fmaf(fhat, c, p);
        const float h = ohat * tanh_(c);

        if (lane < HH) hbuf[lane][s & 63] = h * wc;

        #pragma unroll
        for (int m = 0; m < HH; ++m)
            hs[m] = __int_as_float(__builtin_amdgcn_readlane(__float_as_int(h), m));

        xproj(xn, wih1, wih2, bb1, bb2, xz1, xz2);

        if ((s & 63) == 63) {
            const int sbase = s - 63;
            float d0 = 0.f, d1 = 0.f, d2 = 0.f, d3 = 0.f;
            #pragma unroll
            for (int k = 0; k < HH; k += 4) {
                d0 += hbuf[k    ][lane];
                d1 += hbuf[k + 1][lane];
                d2 += hbuf[k + 2][lane];
                d3 += hbuf[k + 3][lane];
            }
            const float d = (d0 + d1) + (d2 + d3);
            const int t = dir ? (TT - 1 - sbase - lane) : (sbase + lane);
            atomicAdd(&outb[t], d);
        }
    }
}

extern "C" void kernel_launch(void* const* d_in, const int* in_sizes, int n_in,
                              void* d_out, int out_size, void* d_ws, size_t ws_size,
                              hipStream_t stream) {
    const float* x      = (const float*)d_in[0];
    const float* w_ih_f = (const float*)d_in[1];
    const float* w_hh_f = (const float*)d_in[2];
    const float* b_ih_f = (const float*)d_in[3];
    const float* b_hh_f = (const float*)d_in[4];
    const float* w_ih_r = (const float*)d_in[5];
    const float* w_hh_r = (const float*)d_in[6];
    const float* b_ih_r = (const float*)d_in[7];
    const float* b_hh_r = (const float*)d_in[8];
    const float* fc1_w  = (const float*)d_in[9];
    const float* fc1_b  = (const float*)d_in[10];
    const float* fc3_w  = (const float*)d_in[11];
    const float* fc3_b  = (const float*)d_in[12];
    float* out = (float*)d_out;

    const int n = BB * TT;
    init_out_kernel<<<(n + 255) / 256, 256, 0, stream>>>(out, fc1_b, fc3_w, fc3_b, n);

    if (ws_size >= P_BYTES) {
        float* P = (float*)d_ws;
        proj_kernel<<<dim3((BB * TT) / 256, 2), 256, 0, stream>>>(
            x, w_ih_f, b_ih_f, b_hh_f, w_ih_r, b_ih_r, b_hh_r, P);
        lstm_scan_split<<<BB * 2, 64, 0, stream>>>(
            P, w_hh_f, w_hh_r, fc1_w, fc3_w, out);
    } else {
        lstm_scan_fused<<<BB * 2, 64, 0, stream>>>(
            x, w_ih_f, w_hh_f, b_ih_f, b_hh_f,
            w_ih_r, w_hh_r, b_ih_r, b_hh_r,
            fc1_w, fc3_w, out);
    }
}

// Round 4
// 757.524 us; speedup vs baseline: 1.9865x; 1.2894x over previous
//
#include <hip/hip_runtime.h>

#define BB 512
#define TT 1024
#define II 50
#define HH 32
#define CH 16            // steps per chunk (barrier cadence)
#define NCH (TT / CH)    // 64 chunks
#define RSLOT 32         // ring slots = 2 chunks (double buffer)

__device__ __forceinline__ float fast_rcp(float x) { return __builtin_amdgcn_rcpf(x); }
__device__ __forceinline__ float sigm(float x) { return fast_rcp(1.f + __expf(-x)); }
__device__ __forceinline__ float tanh_(float x) {
    return 1.f - 2.f * fast_rcp(1.f + __expf(2.f * x));   // saturates correctly
}

// d_out is poisoned before every launch: init every element to the combined
// FC bias b_comb = fc3_w @ fc1_b + fc3_b (fc1->fc3 is affine-affine; dropout
// is identity in eval). The scan kernel atomicAdds partial dots on top.
__global__ void init_out_kernel(float* __restrict__ out,
                                const float* __restrict__ fc1_b,
                                const float* __restrict__ fc3_w,
                                const float* __restrict__ fc3_b,
                                int n) {
    int idx = blockIdx.x * blockDim.x + threadIdx.x;
    float b = fc3_b[0];
    #pragma unroll
    for (int k = 0; k < 64; ++k) b += fc3_w[k] * fc1_b[k];
    if (idx < n) out[idx] = b;
}

// One workgroup (128 threads = 2 waves) per (batch, direction) sequence.
//   wave 0 = CONSUMER: pure recurrence, LDS+VALU only in the hot loop
//            (no VMEM/SMEM -> no lgkmcnt aliasing with HBM-latency loads).
//   wave 1 = PRODUCER: x loads (VMEM), input projection into LDS ring,
//            deferred-FC flush + atomicAdd.
// Lane L (both waves' gate mapping) owns gate rows L and L+64:
//   L<32:  (i_L, g_L)      L>=32: (f_{L-32}, o_{L-32})
// Only p = sig(i)*tanh(g) crosses halves (low->high); c,h live in high lanes.
__global__ void __launch_bounds__(128, 2) lstm_pc_kernel(
    const float* __restrict__ x,
    const float* __restrict__ w_ih_f, const float* __restrict__ w_hh_f,
    const float* __restrict__ b_ih_f, const float* __restrict__ b_hh_f,
    const float* __restrict__ w_ih_r, const float* __restrict__ w_hh_r,
    const float* __restrict__ b_ih_r, const float* __restrict__ b_hh_r,
    const float* __restrict__ fc1_w, const float* __restrict__ fc3_w,
    float* __restrict__ out)
{
    __shared__ float2 ring[RSLOT][64];    // 16 KB: per-step gate-pair projections
    __shared__ float  xstage[4][52];      // 832 B: x-row broadcast staging
    __shared__ float  hbuf[HH][65];       // 8.3 KB: deferred FC partials (h*wc)

    const int tid  = threadIdx.x;
    const int lane = tid & 63;
    const int wave = tid >> 6;            // 0 consumer, 1 producer
    const int b    = blockIdx.x >> 1;
    const int dir  = blockIdx.x & 1;
    float* outb = out + (size_t)b * TT;

    if (wave == 1) {
        // ================= PRODUCER =================
        const float* w_ih = dir ? w_ih_r : w_ih_f;
        const float* bi   = dir ? b_ih_r : b_ih_f;
        const float* bh   = dir ? b_hh_r : b_hh_f;
        const float* xb   = x + (size_t)b * TT * II;

        float wih1[52], wih2[52];
        #pragma unroll
        for (int m = 0; m < II; ++m) {
            wih1[m] = w_ih[lane * II + m];
            wih2[m] = w_ih[(64 + lane) * II + m];
        }
        wih1[50] = wih1[51] = wih2[50] = wih2[51] = 0.f;  // pad (xstage[50..51]=0)
        const float bb1 = bi[lane] + bh[lane];
        const float bb2 = bi[64 + lane] + bh[64 + lane];

        // per-lane x load: step S -> x[b][t][lane], lane<II
        auto load_x = [&](int S) -> float {
            int Sc = (S < TT) ? S : TT - 1;
            int t  = dir ? (TT - 1 - Sc) : Sc;
            return (lane < II) ? xb[(size_t)t * II + lane] : 0.f;
        };
        // LDS stage write for step S (from xpre ring)
        float xpre[8];
        auto stage_write = [&](int S) {
            if (lane < 52) xstage[S & 3][lane] = (lane < II) ? xpre[S & 7] : 0.f;
        };
        // produce one step: projection -> ring
        auto produce = [&](int S) {
            stage_write(S + 2);                 // value loaded 4 steps ago (vmcnt-covered)
            xpre[(S + 6) & 7] = load_x(S + 6);  // refill VGPR ring (depth 6)
            const float* xs = xstage[S & 3];    // written 2 steps ago (in-order ds)
            float a0 = bb1, a1 = 0.f, c0 = bb2, c1 = 0.f;
            #pragma unroll
            for (int m = 0; m < 52; m += 4) {
                float4 q = *(const float4*)(xs + m);
                a0 = fmaf(q.x, wih1[m    ], a0); c0 = fmaf(q.x, wih2[m    ], c0);
                a1 = fmaf(q.y, wih1[m + 1], a1); c1 = fmaf(q.y, wih2[m + 1], c1);
                a0 = fmaf(q.z, wih1[m + 2], a0); c0 = fmaf(q.z, wih2[m + 2], c0);
                a1 = fmaf(q.w, wih1[m + 3], a1); c1 = fmaf(q.w, wih2[m + 3], c1);
            }
            ring[S & (RSLOT - 1)][lane] = make_float2(a0 + a1, c0 + c1);
        };
        // flush chunk m: 16 outputs, lanes 0..15
        auto flush = [&](int m) {
            if (lane < CH) {
                const int ti  = m * CH + lane;
                const int col = ti & 63;
                float d0 = 0.f, d1 = 0.f, d2 = 0.f, d3 = 0.f;
                #pragma unroll
                for (int k = 0; k < HH; k += 4) {
                    d0 += hbuf[k    ][col];
                    d1 += hbuf[k + 1][col];
                    d2 += hbuf[k + 2][col];
                    d3 += hbuf[k + 3][col];
                }
                const int t = dir ? (TT - 1 - ti) : ti;
                atomicAdd(&outb[t], (d0 + d1) + (d2 + d3));
            }
        };

        // pipeline prologue: loads for steps 0..5, stage steps 0,1
        #pragma unroll
        for (int j = 0; j < 6; ++j) xpre[j] = load_x(j);
        stage_write(0);
        stage_write(1);
        // fill chunk 0
        for (int u = 0; u < CH; ++u) produce(u);
        __syncthreads();

        for (int n = 0; n < NCH; ++n) {
            if (n + 1 < NCH) {
                const int base = (n + 1) * CH;
                for (int u = 0; u < CH; ++u) produce(base + u);
            }
            if (n >= 1) flush(n - 1);
            __syncthreads();
        }
        flush(NCH - 1);
    } else {
        // ================= CONSUMER =================
        const float* w_hh = dir ? w_hh_r : w_hh_f;
        float whh1[HH], whh2[HH];
        #pragma unroll
        for (int m = 0; m < HH; ++m) {
            whh1[m] = w_hh[lane * HH + m];          // row L   (i or f)
            whh2[m] = w_hh[(64 + lane) * HH + m];   // row L+64 (g or o)
        }
        // a2 = A2*sigm(M2*z2)+B2: low lanes tanh(g), high lanes sigm(o)
        const float M2 = (lane < HH) ? 2.f : 1.f;
        const float A2 = M2;
        const float B2 = (lane < HH) ? -1.f : 0.f;

        // fused FC weight for this lane's hidden unit
        float wc = 0.f;
        {
            const int j = dir * HH + (lane & 31);
            #pragma unroll
            for (int n = 0; n < 64; ++n) wc += fc3_w[n] * fc1_w[n * 64 + j];
        }

        float hs[HH];
        #pragma unroll
        for (int m = 0; m < HH; ++m) hs[m] = 0.f;
        float c = 0.f;

        __syncthreads();   // matches producer's prologue barrier

        for (int n = 0; n < NCH; ++n) {
            const int slot0 = (n & 1) * CH;          // ring half for this chunk
            const int col0  = (n & 3) * CH;          // hbuf column group
            #pragma unroll
            for (int u = 0; u < CH; ++u) {
                const float2 xz = ring[slot0 + u][lane];

                float h0 = 0.f, h1 = 0.f, h2 = 0.f, h3 = 0.f;
                float g0 = 0.f, g1 = 0.f, g2 = 0.f, g3 = 0.f;
                #pragma unroll
                for (int m = 0; m < HH; m += 4) {
                    h0 = fmaf(hs[m    ], whh1[m    ], h0); g0 = fmaf(hs[m    ], whh2[m    ], g0);
                    h1 = fmaf(hs[m + 1], whh1[m + 1], h1); g1 = fmaf(hs[m + 1], whh2[m + 1], g1);
                    h2 = fmaf(hs[m + 2], whh1[m + 2], h2); g2 = fmaf(hs[m + 2], whh2[m + 2], g2);
                    h3 = fmaf(hs[m + 3], whh1[m + 3], h3); g3 = fmaf(hs[m + 3], whh2[m + 3], g3);
                }
                const float z1 = xz.x + ((h0 + h1) + (h2 + h3));
                const float z2 = xz.y + ((g0 + g1) + (g2 + g3));

                // low: a1=sig(i), a2=tanh(g); high: a1=sig(f), a2=sig(o)
                const float a1 = sigm(z1);
                const float a2 = fmaf(A2, sigm(M2 * z2), B2);
                const float p  = a1 * a2;            // low lanes: sig(i)*tanh(g)
                const float ph = __shfl_xor(p, 32);  // high lanes receive p (1 crossing)

                // c,h maintained in HIGH lanes (low lanes: bounded garbage, unused)
                c = fmaf(a1, c, ph);                 // high: sig(f)*c + p
                const float h = a2 * tanh_(c);       // high: sig(o)*tanh(c)

                if (lane >= HH) hbuf[lane - HH][col0 + u] = h * wc;

                #pragma unroll
                for (int m = 0; m < HH; ++m)
                    hs[m] = __int_as_float(
                        __builtin_amdgcn_readlane(__float_as_int(h), 32 + m));
            }
            __syncthreads();
        }
    }
}

extern "C" void kernel_launch(void* const* d_in, const int* in_sizes, int n_in,
                              void* d_out, int out_size, void* d_ws, size_t ws_size,
                              hipStream_t stream) {
    const float* x      = (const float*)d_in[0];
    const float* w_ih_f = (const float*)d_in[1];
    const float* w_hh_f = (const float*)d_in[2];
    const float* b_ih_f = (const float*)d_in[3];
    const float* b_hh_f = (const float*)d_in[4];
    const float* w_ih_r = (const float*)d_in[5];
    const float* w_hh_r = (const float*)d_in[6];
    const float* b_ih_r = (const float*)d_in[7];
    const float* b_hh_r = (const float*)d_in[8];
    const float* fc1_w  = (const float*)d_in[9];
    const float* fc1_b  = (const float*)d_in[10];
    const float* fc3_w  = (const float*)d_in[11];
    const float* fc3_b  = (const float*)d_in[12];
    float* out = (float*)d_out;

    const int n = BB * TT;
    init_out_kernel<<<(n + 255) / 256, 256, 0, stream>>>(out, fc1_b, fc3_w, fc3_b, n);

    // 1024 workgroups = (batch, direction); 2 waves each (consumer+producer).
    lstm_pc_kernel<<<BB * 2, 128, 0, stream>>>(
        x, w_ih_f, w_hh_f, b_ih_f, b_hh_f,
        w_ih_r, w_hh_r, b_ih_r, b_hh_r,
        fc1_w, fc3_w, out);
}

// Round 5
// 666.323 us; speedup vs baseline: 2.2584x; 1.1369x over previous
//
#include <hip/hip_runtime.h>

#define BB 512
#define TT 1024
#define II 50
#define HH 32
#define CH 16            // steps per chunk (barrier cadence)
#define NCH (TT / CH)    // 64 chunks
#define RSLOT 32         // ring slots = 2 chunks (double buffer)

typedef float v2f __attribute__((ext_vector_type(2)));

__device__ __forceinline__ float fast_rcp(float x) { return __builtin_amdgcn_rcpf(x); }
__device__ __forceinline__ float sigm(float x) { return fast_rcp(1.f + __expf(-x)); }
__device__ __forceinline__ float tanh_(float x) {
    return 1.f - 2.f * fast_rcp(1.f + __expf(2.f * x));   // saturates correctly
}

// d_out is poisoned before every launch: init every element to the combined
// FC bias b_comb = fc3_w @ fc1_b + fc3_b (fc1->fc3 is affine-affine; dropout
// is identity in eval). The scan kernel atomicAdds partial dots on top.
__global__ void init_out_kernel(float* __restrict__ out,
                                const float* __restrict__ fc1_b,
                                const float* __restrict__ fc3_w,
                                const float* __restrict__ fc3_b,
                                int n) {
    int idx = blockIdx.x * blockDim.x + threadIdx.x;
    float b = fc3_b[0];
    #pragma unroll
    for (int k = 0; k < 64; ++k) b += fc3_w[k] * fc1_b[k];
    if (idx < n) out[idx] = b;
}

// One workgroup (128 threads = 2 waves) per (batch, direction) sequence.
//   wave 0 = CONSUMER: pure recurrence, LDS+VALU only in the hot loop.
//   wave 1 = PRODUCER: x loads (VMEM), input projection into LDS ring,
//            deferred-FC flush + atomicAdd.
// Lane L owns gate rows L and L+64 (both packed as one float2 accumulator):
//   L<32:  (i_L, g_L)      L>=32: (f_{L-32}, o_{L-32})
// Only p = sig(i)*tanh(g) crosses halves (low->high); c,h live in high lanes.
__global__ void __launch_bounds__(128, 2) lstm_pc_kernel(
    const float* __restrict__ x,
    const float* __restrict__ w_ih_f, const float* __restrict__ w_hh_f,
    const float* __restrict__ b_ih_f, const float* __restrict__ b_hh_f,
    const float* __restrict__ w_ih_r, const float* __restrict__ w_hh_r,
    const float* __restrict__ b_ih_r, const float* __restrict__ b_hh_r,
    const float* __restrict__ fc1_w, const float* __restrict__ fc3_w,
    float* __restrict__ out)
{
    __shared__ v2f   ring[RSLOT][64];     // 16 KB: per-step gate-pair projections
    __shared__ float xstage[4][52];       // 832 B: x-row broadcast staging
    __shared__ float hbuf[HH][65];        // 8.3 KB: deferred FC partials (h*wc)

    const int tid  = threadIdx.x;
    const int lane = tid & 63;
    const int wave = tid >> 6;            // 0 consumer, 1 producer
    const int b    = blockIdx.x >> 1;
    const int dir  = blockIdx.x & 1;
    float* outb = out + (size_t)b * TT;

    if (wave == 1) {
        // ================= PRODUCER =================
        const float* w_ih = dir ? w_ih_r : w_ih_f;
        const float* bi   = dir ? b_ih_r : b_ih_f;
        const float* bh   = dir ? b_hh_r : b_hh_f;
        const float* xb   = x + (size_t)b * TT * II;

        // weight PAIRS: wihp[m] = {w[row L][m], w[row L+64][m]} -> v_pk_fma_f32
        v2f wihp[52];
        #pragma unroll
        for (int m = 0; m < II; ++m) {
            wihp[m].x = w_ih[lane * II + m];
            wihp[m].y = w_ih[(64 + lane) * II + m];
        }
        wihp[50] = (v2f){0.f, 0.f};
        wihp[51] = (v2f){0.f, 0.f};
        const v2f bbp = {bi[lane] + bh[lane], bi[64 + lane] + bh[64 + lane]};

        auto load_x = [&](int S) -> float {
            int Sc = (S < TT) ? S : TT - 1;
            int t  = dir ? (TT - 1 - Sc) : Sc;
            return (lane < II) ? xb[(size_t)t * II + lane] : 0.f;
        };
        float xpre[8];
        auto stage_write = [&](int S) {
            if (lane < 52) xstage[S & 3][lane] = (lane < II) ? xpre[S & 7] : 0.f;
        };
        auto produce = [&](int S) {
            stage_write(S + 2);                 // value loaded 4 steps ago
            xpre[(S + 6) & 7] = load_x(S + 6);  // refill VGPR ring (depth 6)
            const float* xs = xstage[S & 3];    // written 2 steps ago (in-order ds)
            v2f a0 = bbp, a1 = {0.f, 0.f}, a2 = {0.f, 0.f}, a3 = {0.f, 0.f};
            #pragma unroll
            for (int m = 0; m < 52; m += 4) {
                float4 q = *(const float4*)(xs + m);
                v2f q0 = {q.x, q.x}, q1 = {q.y, q.y}, q2 = {q.z, q.z}, q3 = {q.w, q.w};
                a0 = __builtin_elementwise_fma(q0, wihp[m    ], a0);
                a1 = __builtin_elementwise_fma(q1, wihp[m + 1], a1);
                a2 = __builtin_elementwise_fma(q2, wihp[m + 2], a2);
                a3 = __builtin_elementwise_fma(q3, wihp[m + 3], a3);
            }
            ring[S & (RSLOT - 1)][lane] = (a0 + a1) + (a2 + a3);
        };
        auto flush = [&](int m) {
            if (lane < CH) {
                const int ti  = m * CH + lane;
                const int col = ti & 63;
                float d0 = 0.f, d1 = 0.f, d2 = 0.f, d3 = 0.f;
                #pragma unroll
                for (int k = 0; k < HH; k += 4) {
                    d0 += hbuf[k    ][col];
                    d1 += hbuf[k + 1][col];
                    d2 += hbuf[k + 2][col];
                    d3 += hbuf[k + 3][col];
                }
                const int t = dir ? (TT - 1 - ti) : ti;
                atomicAdd(&outb[t], (d0 + d1) + (d2 + d3));
            }
        };

        #pragma unroll
        for (int j = 0; j < 6; ++j) xpre[j] = load_x(j);
        stage_write(0);
        stage_write(1);
        for (int u = 0; u < CH; ++u) produce(u);
        __syncthreads();

        for (int n = 0; n < NCH; ++n) {
            if (n + 1 < NCH) {
                const int base = (n + 1) * CH;
                for (int u = 0; u < CH; ++u) produce(base + u);
            }
            if (n >= 1) flush(n - 1);
            __syncthreads();
        }
        flush(NCH - 1);
    } else {
        // ================= CONSUMER =================
        const float* w_hh = dir ? w_hh_r : w_hh_f;
        v2f whhp[HH];   // {row L, row L+64} pairs
        #pragma unroll
        for (int m = 0; m < HH; ++m) {
            whhp[m].x = w_hh[lane * HH + m];
            whhp[m].y = w_hh[(64 + lane) * HH + m];
        }
        // a2 = A2*sigm(M2*z2)+B2: low lanes tanh(g), high lanes sigm(o)
        const float M2 = (lane < HH) ? 2.f : 1.f;
        const float A2 = M2;
        const float B2 = (lane < HH) ? -1.f : 0.f;

        float wc = 0.f;
        {
            const int j = dir * HH + (lane & 31);
            #pragma unroll
            for (int n = 0; n < 64; ++n) wc += fc3_w[n] * fc1_w[n * 64 + j];
        }

        float hs[HH];
        #pragma unroll
        for (int m = 0; m < HH; ++m) hs[m] = 0.f;
        float c = 0.f;

        __syncthreads();   // matches producer's prologue barrier

        for (int n = 0; n < NCH; ++n) {
            const int slot0 = (n & 1) * CH;
            const int col0  = (n & 3) * CH;

            // preload whole chunk (independent of recurrence -> off-chain)
            v2f xzbuf[CH];
            #pragma unroll
            for (int u = 0; u < CH; ++u) xzbuf[u] = ring[slot0 + u][lane];

            #pragma unroll
            for (int u = 0; u < CH; ++u) {
                v2f a0 = xzbuf[u], a1 = {0.f, 0.f}, a2v = {0.f, 0.f}, a3 = {0.f, 0.f};
                #pragma unroll
                for (int m = 0; m < HH; m += 4) {
                    v2f h0 = {hs[m    ], hs[m    ]};
                    v2f h1 = {hs[m + 1], hs[m + 1]};
                    v2f h2 = {hs[m + 2], hs[m + 2]};
                    v2f h3 = {hs[m + 3], hs[m + 3]};
                    a0  = __builtin_elementwise_fma(h0, whhp[m    ], a0);
                    a1  = __builtin_elementwise_fma(h1, whhp[m + 1], a1);
                    a2v = __builtin_elementwise_fma(h2, whhp[m + 2], a2v);
                    a3  = __builtin_elementwise_fma(h3, whhp[m + 3], a3);
                }
                const v2f z12 = (a0 + a1) + (a2v + a3);
                const float z1 = z12.x;
                const float z2 = z12.y;

                // low: a1=sig(i), a2=tanh(g); high: a1=sig(f), a2=sig(o)
                const float g1 = sigm(z1);
                const float g2 = fmaf(A2, sigm(M2 * z2), B2);
                const float p  = g1 * g2;            // low lanes: sig(i)*tanh(g)
                const float ph = __shfl_xor(p, 32);  // high lanes receive p

                // c,h maintained in HIGH lanes (low lanes: bounded garbage)
                c = fmaf(g1, c, ph);                 // high: sig(f)*c + p
                const float h = g2 * tanh_(c);       // high: sig(o)*tanh(c)

                if (lane >= HH) hbuf[lane - HH][col0 + u] = h * wc;

                #pragma unroll
                for (int m = 0; m < HH; ++m)
                    hs[m] = __int_as_float(
                        __builtin_amdgcn_readlane(__float_as_int(h), 32 + m));
            }
            __syncthreads();
        }
    }
}

extern "C" void kernel_launch(void* const* d_in, const int* in_sizes, int n_in,
                              void* d_out, int out_size, void* d_ws, size_t ws_size,
                              hipStream_t stream) {
    const float* x      = (const float*)d_in[0];
    const float* w_ih_f = (const float*)d_in[1];
    const float* w_hh_f = (const float*)d_in[2];
    const float* b_ih_f = (const float*)d_in[3];
    const float* b_hh_f = (const float*)d_in[4];
    const float* w_ih_r = (const float*)d_in[5];
    const float* w_hh_r = (const float*)d_in[6];
    const float* b_ih_r = (const float*)d_in[7];
    const float* b_hh_r = (const float*)d_in[8];
    const float* fc1_w  = (const float*)d_in[9];
    const float* fc1_b  = (const float*)d_in[10];
    const float* fc3_w  = (const float*)d_in[11];
    const float* fc3_b  = (const float*)d_in[12];
    float* out = (float*)d_out;

    const int n = BB * TT;
    init_out_kernel<<<(n + 255) / 256, 256, 0, stream>>>(out, fc1_b, fc3_w, fc3_b, n);

    // 1024 workgroups = (batch, direction); 2 waves each (consumer+producer).
    lstm_pc_kernel<<<BB * 2, 128, 0, stream>>>(
        x, w_ih_f, w_hh_f, b_ih_f, b_hh_f,
        w_ih_r, w_hh_r, b_ih_r, b_hh_r,
        fc1_w, fc3_w, out);
}

// Round 7
// 580.104 us; speedup vs baseline: 2.5941x; 1.1486x over previous
//
#include <hip/hip_runtime.h>

#define BB 512
#define TT 1024
#define II 50
#define HH 32
#define CH 16            // steps per chunk (barrier cadence)
#define NCH (TT / CH)    // 64 chunks
#define RSLOT 32         // ring slots = 2 chunks (double buffer)

typedef float v2f __attribute__((ext_vector_type(2)));

__device__ __forceinline__ float fast_rcp(float x) { return __builtin_amdgcn_rcpf(x); }
__device__ __forceinline__ float sigm(float x) { return fast_rcp(1.f + __expf(-x)); }
__device__ __forceinline__ float tanh_(float x) {
    return 1.f - 2.f * fast_rcp(1.f + __expf(2.f * x));   // saturates correctly
}
__device__ __forceinline__ float hadd(v2f v) { return v.x + v.y; }

// d_out is poisoned before every launch: init every element to the combined
// FC bias b_comb = fc3_w @ fc1_b + fc3_b (fc1->fc3 is affine-affine; dropout
// is identity in eval). The scan kernel atomicAdds partial dots on top.
__global__ void init_out_kernel(float* __restrict__ out,
                                const float* __restrict__ fc1_b,
                                const float* __restrict__ fc3_w,
                                const float* __restrict__ fc3_b,
                                int n) {
    int idx = blockIdx.x * blockDim.x + threadIdx.x;
    float b = fc3_b[0];
    #pragma unroll
    for (int k = 0; k < 64; ++k) b += fc3_w[k] * fc1_b[k];
    if (idx < n) out[idx] = b;
}

// One workgroup (128 threads = 2 waves) per (batch, direction) sequence.
//   wave 0 = CONSUMER: pure recurrence, LDS+VALU only in the hot loop.
//   wave 1 = PRODUCER: x loads (VMEM), input projection into LDS ring,
//            deferred-FC flush + atomicAdd.
// Lane L owns gate rows L and L+64:
//   L<32:  (i_L, g_L)      L>=32: (f_{L-32}, o_{L-32})
// All pk_fma are K-PACKED ({v_m,v_{m+1}} x {w[m],w[m+1]}): no splat movs.
// h broadcast: high lanes ds_write hst, next step all lanes read b128
// broadcast. CRITICAL: an empty asm memory clobber at the end of each
// consumer step pins the hst store->load order — without it the compiler
// (licensed by the float4/float type-pun) hoists next step's h4 loads above
// this step's hst store when unrolling (round-6 failure, absmax 0.14).
__global__ void __launch_bounds__(128, 2) lstm_pc_kernel(
    const float* __restrict__ x,
    const float* __restrict__ w_ih_f, const float* __restrict__ w_hh_f,
    const float* __restrict__ b_ih_f, const float* __restrict__ b_hh_f,
    const float* __restrict__ w_ih_r, const float* __restrict__ w_hh_r,
    const float* __restrict__ b_ih_r, const float* __restrict__ b_hh_r,
    const float* __restrict__ fc1_w, const float* __restrict__ fc3_w,
    float* __restrict__ out)
{
    __shared__ v2f   ring[RSLOT][64];     // 16 KB: per-step gate-pair projections
    __shared__ float xstage[4][52];       // 832 B: x-row broadcast staging
    __shared__ float hbuf[HH][65];        // 8.3 KB: deferred FC partials (h*wc)
    __shared__ __align__(16) float hst[HH];  // 128 B: h(t-1) broadcast stage

    const int tid  = threadIdx.x;
    const int lane = tid & 63;
    const int wave = tid >> 6;            // 0 consumer, 1 producer
    const int b    = blockIdx.x >> 1;
    const int dir  = blockIdx.x & 1;
    float* outb = out + (size_t)b * TT;

    if (wave == 1) {
        // ================= PRODUCER =================
        const float* w_ih = dir ? w_ih_r : w_ih_f;
        const float* bi   = dir ? b_ih_r : b_ih_f;
        const float* bh   = dir ? b_hh_r : b_hh_f;
        const float* xb   = x + (size_t)b * TT * II;

        // K-packed weight pairs: wih1p[j] = {w[L][2j], w[L][2j+1]}
        v2f wih1p[26], wih2p[26];
        #pragma unroll
        for (int j = 0; j < 26; ++j) {
            const int m = 2 * j;
            wih1p[j].x = (m     < II) ? w_ih[lane * II + m]     : 0.f;
            wih1p[j].y = (m + 1 < II) ? w_ih[lane * II + m + 1] : 0.f;
            wih2p[j].x = (m     < II) ? w_ih[(64 + lane) * II + m]     : 0.f;
            wih2p[j].y = (m + 1 < II) ? w_ih[(64 + lane) * II + m + 1] : 0.f;
        }
        const float bb1 = bi[lane] + bh[lane];
        const float bb2 = bi[64 + lane] + bh[64 + lane];

        auto load_x = [&](int S) -> float {
            int Sc = (S < TT) ? S : TT - 1;
            int t  = dir ? (TT - 1 - Sc) : Sc;
            return (lane < II) ? xb[(size_t)t * II + lane] : 0.f;
        };
        float xpre[8];
        auto stage_write = [&](int S) {
            if (lane < 52) xstage[S & 3][lane] = (lane < II) ? xpre[S & 7] : 0.f;
        };
        auto produce = [&](int S) {
            stage_write(S + 2);                 // value loaded 4 steps ago
            xpre[(S + 6) & 7] = load_x(S + 6);  // refill VGPR ring (depth 6)
            const float* xs = xstage[S & 3];    // written 2 steps ago (in-order ds)
            v2f a0 = {bb1, 0.f}, a1 = {0.f, 0.f};
            v2f b0 = {bb2, 0.f}, b1 = {0.f, 0.f};
            #pragma unroll
            for (int m = 0; m < 13; ++m) {
                float4 q = *(const float4*)(xs + 4 * m);   // broadcast b128
                v2f qa = {q.x, q.y};                       // adjacent regs, free
                v2f qb = {q.z, q.w};
                a0 = __builtin_elementwise_fma(qa, wih1p[2 * m    ], a0);
                b0 = __builtin_elementwise_fma(qa, wih2p[2 * m    ], b0);
                a1 = __builtin_elementwise_fma(qb, wih1p[2 * m + 1], a1);
                b1 = __builtin_elementwise_fma(qb, wih2p[2 * m + 1], b1);
            }
            ring[S & (RSLOT - 1)][lane] = (v2f){hadd(a0 + a1), hadd(b0 + b1)};
        };
        auto flush = [&](int m) {
            if (lane < CH) {
                const int ti  = m * CH + lane;
                const int col = ti & 63;
                float d0 = 0.f, d1 = 0.f, d2 = 0.f, d3 = 0.f;
                #pragma unroll
                for (int k = 0; k < HH; k += 4) {
                    d0 += hbuf[k    ][col];
                    d1 += hbuf[k + 1][col];
                    d2 += hbuf[k + 2][col];
                    d3 += hbuf[k + 3][col];
                }
                const int t = dir ? (TT - 1 - ti) : ti;
                atomicAdd(&outb[t], (d0 + d1) + (d2 + d3));
            }
        };

        #pragma unroll
        for (int j = 0; j < 6; ++j) xpre[j] = load_x(j);
        stage_write(0);
        stage_write(1);
        for (int u = 0; u < CH; ++u) produce(u);
        __syncthreads();

        for (int n = 0; n < NCH; ++n) {
            if (n + 1 < NCH) {
                const int base = (n + 1) * CH;
                for (int u = 0; u < CH; ++u) produce(base + u);
            }
            if (n >= 1) flush(n - 1);
            __syncthreads();
        }
        flush(NCH - 1);
    } else {
        // ================= CONSUMER =================
        const float* w_hh = dir ? w_hh_r : w_hh_f;
        // K-packed hh weight pairs: whh1p[j] = {w[L][2j], w[L][2j+1]}
        v2f whh1p[16], whh2p[16];
        #pragma unroll
        for (int j = 0; j < 16; ++j) {
            whh1p[j].x = w_hh[lane * HH + 2 * j];
            whh1p[j].y = w_hh[lane * HH + 2 * j + 1];
            whh2p[j].x = w_hh[(64 + lane) * HH + 2 * j];
            whh2p[j].y = w_hh[(64 + lane) * HH + 2 * j + 1];
        }
        // g2 = A2*sigm(M2*z2)+B2: low lanes tanh(g), high lanes sigm(o)
        const float M2 = (lane < HH) ? 2.f : 1.f;
        const float A2 = M2;
        const float B2 = (lane < HH) ? -1.f : 0.f;

        float wc = 0.f;
        {
            const int j = dir * HH + (lane & 31);
            #pragma unroll
            for (int n = 0; n < 64; ++n) wc += fc3_w[n] * fc1_w[n * 64 + j];
        }

        if (lane < HH) hst[lane] = 0.f;   // h(-1) = 0 (same-wave in-order DS)
        float c = 0.f;

        __syncthreads();   // matches producer's prologue barrier

        for (int n = 0; n < NCH; ++n) {
            const int slot0 = (n & 1) * CH;
            const int col0  = (n & 3) * CH;

            // chunk-top ring preload: all 16 reads issue before any fence
            v2f xzbuf[CH];
            #pragma unroll
            for (int u = 0; u < CH; ++u) xzbuf[u] = ring[slot0 + u][lane];

            #pragma unroll
            for (int u = 0; u < CH; ++u) {
                // h(t-1) broadcast: 8x b128 same-address reads (LDS pipe)
                float4 h4[8];
                #pragma unroll
                for (int j = 0; j < 8; ++j) h4[j] = *(const float4*)&hst[4 * j];

                v2f a0 = {0.f, 0.f}, a1 = {0.f, 0.f};
                v2f b0 = {0.f, 0.f}, b1 = {0.f, 0.f};
                #pragma unroll
                for (int j = 0; j < 8; ++j) {
                    v2f p0 = {h4[j].x, h4[j].y};        // adjacent regs, free
                    v2f p1 = {h4[j].z, h4[j].w};
                    a0 = __builtin_elementwise_fma(p0, whh1p[2 * j    ], a0);
                    b0 = __builtin_elementwise_fma(p0, whh2p[2 * j    ], b0);
                    a1 = __builtin_elementwise_fma(p1, whh1p[2 * j + 1], a1);
                    b1 = __builtin_elementwise_fma(p1, whh2p[2 * j + 1], b1);
                }
                const v2f xz = xzbuf[u];                // consumed late: overlaps dot
                const float z1 = xz.x + hadd(a0 + a1);
                const float z2 = xz.y + hadd(b0 + b1);

                // low: g1=sig(i), g2=tanh(g); high: g1=sig(f), g2=sig(o)
                const float g1 = sigm(z1);
                const float g2 = fmaf(A2, sigm(M2 * z2), B2);
                const float p  = g1 * g2;            // low lanes: sig(i)*tanh(g)
                const float ph = __shfl_xor(p, 32);  // high lanes receive p

                // c,h maintained in HIGH lanes (low lanes: bounded garbage)
                c = fmaf(g1, c, ph);                 // high: sig(f)*c + p
                const float h = g2 * tanh_(c);       // high: sig(o)*tanh(c)

                if (lane >= HH) {
                    hst[lane - HH] = h;                    // next step's broadcast
                    hbuf[lane - HH][col0 + u] = h * wc;    // deferred FC
                }
                // ordering fence: store(u) may not sink, loads(u+1) may not
                // hoist. Zero instructions emitted.
                asm volatile("" ::: "memory");
            }
            __syncthreads();
        }
    }
}

extern "C" void kernel_launch(void* const* d_in, const int* in_sizes, int n_in,
                              void* d_out, int out_size, void* d_ws, size_t ws_size,
                              hipStream_t stream) {
    const float* x      = (const float*)d_in[0];
    const float* w_ih_f = (const float*)d_in[1];
    const float* w_hh_f = (const float*)d_in[2];
    const float* b_ih_f = (const float*)d_in[3];
    const float* b_hh_f = (const float*)d_in[4];
    const float* w_ih_r = (const float*)d_in[5];
    const float* w_hh_r = (const float*)d_in[6];
    const float* b_ih_r = (const float*)d_in[7];
    const float* b_hh_r = (const float*)d_in[8];
    const float* fc1_w  = (const float*)d_in[9];
    const float* fc1_b  = (const float*)d_in[10];
    const float* fc3_w  = (const float*)d_in[11];
    const float* fc3_b  = (const float*)d_in[12];
    float* out = (float*)d_out;

    const int n = BB * TT;
    init_out_kernel<<<(n + 255) / 256, 256, 0, stream>>>(out, fc1_b, fc3_w, fc3_b, n);

    // 1024 workgroups = (batch, direction); 2 waves each (consumer+producer).
    lstm_pc_kernel<<<BB * 2, 128, 0, stream>>>(
        x, w_ih_f, w_hh_f, b_ih_f, b_hh_f,
        w_ih_r, w_hh_r, b_ih_r, b_hh_r,
        fc1_w, fc3_w, out);
}

// Round 8
// 451.353 us; speedup vs baseline: 3.3341x; 1.2853x over previous
//
#include <hip/hip_runtime.h>

#define BB 512
#define TT 1024
#define II 50
#define HH 32
#define CH 16            // steps per chunk (barrier cadence; = MFMA M)
#define NCH (TT / CH)    // 64 chunks
#define RSLOT 32         // ring slots = 2 chunks (double buffer)

typedef float v2f __attribute__((ext_vector_type(2)));
typedef float v4f __attribute__((ext_vector_type(4)));
typedef short v8s __attribute__((ext_vector_type(8)));   // 8 bf16 (4 VGPRs)

__device__ __forceinline__ float fast_rcp(float x) { return __builtin_amdgcn_rcpf(x); }
__device__ __forceinline__ float sigm(float x) { return fast_rcp(1.f + __expf(-x)); }
__device__ __forceinline__ float tanh_(float x) {
    return 1.f - 2.f * fast_rcp(1.f + __expf(2.f * x));   // saturates correctly
}
__device__ __forceinline__ float hadd(v2f v) { return v.x + v.y; }
__device__ __forceinline__ short bf16rne(float f) {      // fp32 -> bf16 RNE
    unsigned u = __float_as_uint(f);
    u += 0x7FFF + ((u >> 16) & 1);
    return (short)(u >> 16);
}

// d_out is poisoned before every launch: init every element to the combined
// FC bias b_comb = fc3_w @ fc1_b + fc3_b (fc1->fc3 is affine-affine; dropout
// is identity in eval). The scan kernel atomicAdds partial dots on top.
__global__ void init_out_kernel(float* __restrict__ out,
                                const float* __restrict__ fc1_b,
                                const float* __restrict__ fc3_w,
                                const float* __restrict__ fc3_b,
                                int n) {
    int idx = blockIdx.x * blockDim.x + threadIdx.x;
    float b = fc3_b[0];
    #pragma unroll
    for (int k = 0; k < 64; ++k) b += fc3_w[k] * fc1_b[k];
    if (idx < n) out[idx] = b;
}

// One workgroup (128 threads = 2 waves) per (batch, direction) sequence.
//   wave 0 = CONSUMER: fp32 recurrence, LDS+VALU only in the hot loop.
//   wave 1 = PRODUCER: ih projection via bf16 MFMA (16 MFMA per 16-step
//            chunk instead of 52 pk_fma per STEP), plus FC flush+atomicAdd.
// Consumer lane L owns gate rows L and L+64:
//   L<32:  (i_L, g_L)      L>=32: (f_{L-32}, o_{L-32})
// Ring is flat [slot][128] with gate-pair interleave: gate n<64 -> col 2n,
// gate n>=64 -> col 2(n-64)+1, so consumer reads one b64 = {z_L, z_{64+L}}.
// Bias is seeded in the consumer's hh accumulators (MFMA output is biasless).
// MFMA layouts (guide-verified m89/m118/m120):
//   A (16x32): m=lane&15, k=(lane>>4)*8+j     (8 bf16/lane)
//   B (32x16): n=lane&15, k=(lane>>4)*8+j
//   D (16x16): m=(lane>>4)*4+reg, n=lane&15   (4 fp32/lane)
// CRITICAL (round-6 lesson): empty asm memory clobber at the end of each
// consumer step pins the hst store->load order across unrolled steps.
__global__ void __launch_bounds__(128, 2) lstm_pc_kernel(
    const float* __restrict__ x,
    const float* __restrict__ w_ih_f, const float* __restrict__ w_hh_f,
    const float* __restrict__ b_ih_f, const float* __restrict__ b_hh_f,
    const float* __restrict__ w_ih_r, const float* __restrict__ w_hh_r,
    const float* __restrict__ b_ih_r, const float* __restrict__ b_hh_r,
    const float* __restrict__ fc1_w, const float* __restrict__ fc3_w,
    float* __restrict__ out)
{
    __shared__ float ringF[RSLOT * 128];     // 16 KB: per-step gate projections
    __shared__ float hbuf[HH][65];           // 8.3 KB: deferred FC partials
    __shared__ __align__(16) float hst[HH];  // 128 B: h(t-1) broadcast stage

    const int tid  = threadIdx.x;
    const int lane = tid & 63;
    const int wave = tid >> 6;            // 0 consumer, 1 producer
    const int b    = blockIdx.x >> 1;
    const int dir  = blockIdx.x & 1;
    float* outb = out + (size_t)b * TT;

    if (wave == 1) {
        // ================= PRODUCER (MFMA ih projection) =================
        const float* w_ih = dir ? w_ih_r : w_ih_f;
        const float* xb   = x + (size_t)b * TT * II;
        const int nl = lane & 15;         // A: m / B: n / D: n
        const int q  = lane >> 4;         // quad 0..3

        // B fragments (persistent): Bf[nt][kf], n = nt*16+nl, k = kf*32+q*8+j
        v8s Bf[8][2];
        #pragma unroll
        for (int nt = 0; nt < 8; ++nt) {
            const int n = nt * 16 + nl;
            #pragma unroll
            for (int kf = 0; kf < 2; ++kf)
                #pragma unroll
                for (int j = 0; j < 8; ++j) {
                    const int k = kf * 32 + q * 8 + j;
                    Bf[nt][kf][j] = (k < II) ? bf16rne(w_ih[n * II + k]) : (short)0;
                }
        }

        // produce chunk c: fills ring slots for steps c*CH .. c*CH+15
        auto produce_chunk = [&](int c) {
            const int S = c * CH + nl;                 // this lane's A-row step
            const int t = dir ? (TT - 1 - S) : S;
            const float* xr = xb + (size_t)t * II;
            v8s A0, A1;
            #pragma unroll
            for (int j = 0; j < 8; ++j) A0[j] = bf16rne(xr[q * 8 + j]);
            #pragma unroll
            for (int j = 0; j < 8; ++j) {
                const int k = 32 + q * 8 + j;
                A1[j] = (k < II) ? bf16rne(xr[k]) : (short)0;
            }
            #pragma unroll
            for (int nt = 0; nt < 8; ++nt) {
                v4f acc = {0.f, 0.f, 0.f, 0.f};
                acc = __builtin_amdgcn_mfma_f32_16x16x32_bf16(A0, Bf[nt][0], acc, 0, 0, 0);
                acc = __builtin_amdgcn_mfma_f32_16x16x32_bf16(A1, Bf[nt][1], acc, 0, 0, 0);
                const int nn   = nt * 16 + nl;
                const int cidx = (nn < 64) ? 2 * nn : 2 * (nn - 64) + 1;
                #pragma unroll
                for (int r = 0; r < 4; ++r) {
                    const int slot = (c * CH + q * 4 + r) & (RSLOT - 1);
                    ringF[slot * 128 + cidx] = acc[r];
                }
            }
        };
        // flush chunk m: 16 outputs, lanes 0..15
        auto flush = [&](int m) {
            if (lane < CH) {
                const int ti  = m * CH + lane;
                const int col = ti & 63;
                float d0 = 0.f, d1 = 0.f, d2 = 0.f, d3 = 0.f;
                #pragma unroll
                for (int k = 0; k < HH; k += 4) {
                    d0 += hbuf[k    ][col];
                    d1 += hbuf[k + 1][col];
                    d2 += hbuf[k + 2][col];
                    d3 += hbuf[k + 3][col];
                }
                const int t = dir ? (TT - 1 - ti) : ti;
                atomicAdd(&outb[t], (d0 + d1) + (d2 + d3));
            }
        };

        produce_chunk(0);
        __syncthreads();
        for (int n = 0; n < NCH; ++n) {
            if (n + 1 < NCH) produce_chunk(n + 1);
            if (n >= 1) flush(n - 1);
            __syncthreads();
        }
        flush(NCH - 1);
    } else {
        // ================= CONSUMER (fp32 recurrence) =================
        const float* w_hh = dir ? w_hh_r : w_hh_f;
        const float* bi   = dir ? b_ih_r : b_ih_f;
        const float* bh   = dir ? b_hh_r : b_hh_f;
        // K-packed hh weight pairs: whh1p[j] = {w[L][2j], w[L][2j+1]}
        v2f whh1p[16], whh2p[16];
        #pragma unroll
        for (int j = 0; j < 16; ++j) {
            whh1p[j].x = w_hh[lane * HH + 2 * j];
            whh1p[j].y = w_hh[lane * HH + 2 * j + 1];
            whh2p[j].x = w_hh[(64 + lane) * HH + 2 * j];
            whh2p[j].y = w_hh[(64 + lane) * HH + 2 * j + 1];
        }
        const float bb1 = bi[lane] + bh[lane];          // bias, gate row L
        const float bb2 = bi[64 + lane] + bh[64 + lane]; // bias, gate row L+64
        // g2 = A2*sigm(M2*z2)+B2: low lanes tanh(g), high lanes sigm(o)
        const float M2 = (lane < HH) ? 2.f : 1.f;
        const float A2 = M2;
        const float B2 = (lane < HH) ? -1.f : 0.f;

        float wc = 0.f;
        {
            const int j = dir * HH + (lane & 31);
            #pragma unroll
            for (int n = 0; n < 64; ++n) wc += fc3_w[n] * fc1_w[n * 64 + j];
        }

        if (lane < HH) hst[lane] = 0.f;   // h(-1) = 0 (same-wave in-order DS)
        float c = 0.f;

        __syncthreads();   // matches producer's prologue barrier

        for (int n = 0; n < NCH; ++n) {
            const int slot0 = (n & 1) * CH;
            const int col0  = (n & 3) * CH;

            // chunk-top ring preload: all 16 b64 reads issue before any fence
            v2f xzbuf[CH];
            #pragma unroll
            for (int u = 0; u < CH; ++u)
                xzbuf[u] = *(const v2f*)&ringF[(slot0 + u) * 128 + 2 * lane];

            #pragma unroll
            for (int u = 0; u < CH; ++u) {
                // h(t-1) broadcast: 8x b128 same-address reads (LDS pipe)
                float4 h4[8];
                #pragma unroll
                for (int j = 0; j < 8; ++j) h4[j] = *(const float4*)&hst[4 * j];

                v2f a0 = {bb1, 0.f}, a1 = {0.f, 0.f};   // bias seeded here
                v2f b0 = {bb2, 0.f}, b1 = {0.f, 0.f};
                #pragma unroll
                for (int j = 0; j < 8; ++j) {
                    v2f p0 = {h4[j].x, h4[j].y};        // adjacent regs, free
                    v2f p1 = {h4[j].z, h4[j].w};
                    a0 = __builtin_elementwise_fma(p0, whh1p[2 * j    ], a0);
                    b0 = __builtin_elementwise_fma(p0, whh2p[2 * j    ], b0);
                    a1 = __builtin_elementwise_fma(p1, whh1p[2 * j + 1], a1);
                    b1 = __builtin_elementwise_fma(p1, whh2p[2 * j + 1], b1);
                }
                const v2f xz = xzbuf[u];                // consumed late: overlaps dot
                const float z1 = xz.x + hadd(a0 + a1);
                const float z2 = xz.y + hadd(b0 + b1);

                // low: g1=sig(i), g2=tanh(g); high: g1=sig(f), g2=sig(o)
                const float g1 = sigm(z1);
                const float g2 = fmaf(A2, sigm(M2 * z2), B2);
                const float p  = g1 * g2;            // low lanes: sig(i)*tanh(g)
                const float ph = __shfl_xor(p, 32);  // high lanes receive p

                // c,h maintained in HIGH lanes (low lanes: bounded garbage)
                c = fmaf(g1, c, ph);                 // high: sig(f)*c + p
                const float h = g2 * tanh_(c);       // high: sig(o)*tanh(c)

                if (lane >= HH) {
                    hst[lane - HH] = h;                    // next step's broadcast
                    hbuf[lane - HH][col0 + u] = h * wc;    // deferred FC
                }
                // ordering fence: store(u) may not sink, loads(u+1) may not
                // hoist. Zero instructions emitted.
                asm volatile("" ::: "memory");
            }
            __syncthreads();
        }
    }
}

extern "C" void kernel_launch(void* const* d_in, const int* in_sizes, int n_in,
                              void* d_out, int out_size, void* d_ws, size_t ws_size,
                              hipStream_t stream) {
    const float* x      = (const float*)d_in[0];
    const float* w_ih_f = (const float*)d_in[1];
    const float* w_hh_f = (const float*)d_in[2];
    const float* b_ih_f = (const float*)d_in[3];
    const float* b_hh_f = (const float*)d_in[4];
    const float* w_ih_r = (const float*)d_in[5];
    const float* w_hh_r = (const float*)d_in[6];
    const float* b_ih_r = (const float*)d_in[7];
    const float* b_hh_r = (const float*)d_in[8];
    const float* fc1_w  = (const float*)d_in[9];
    const float* fc1_b  = (const float*)d_in[10];
    const float* fc3_w  = (const float*)d_in[11];
    const float* fc3_b  = (const float*)d_in[12];
    float* out = (float*)d_out;

    const int n = BB * TT;
    init_out_kernel<<<(n + 255) / 256, 256, 0, stream>>>(out, fc1_b, fc3_w, fc3_b, n);

    // 1024 workgroups = (batch, direction); 2 waves each (consumer+producer).
    lstm_pc_kernel<<<BB * 2, 128, 0, stream>>>(
        x, w_ih_f, w_hh_f, b_ih_f, b_hh_f,
        w_ih_r, w_hh_r, b_ih_r, b_hh_r,
        fc1_w, fc3_w, out);
}

// Round 9
// 428.939 us; speedup vs baseline: 3.5083x; 1.0523x over previous
//
#include <hip/hip_runtime.h>

#define BB 512
#define TT 1024
#define II 50
#define HH 32
#define CH 16            // steps per chunk (barrier cadence; = MFMA M)
#define NCH (TT / CH)    // 64 chunks
#define RSLOT 32         // ring slots = 2 chunks (double buffer)

typedef float v2f __attribute__((ext_vector_type(2)));
typedef float v4f __attribute__((ext_vector_type(4)));
typedef short v8s __attribute__((ext_vector_type(8)));   // 8 bf16 (4 VGPRs)

__device__ __forceinline__ float fast_rcp(float x) { return __builtin_amdgcn_rcpf(x); }
__device__ __forceinline__ float sigm(float x) { return fast_rcp(1.f + __expf(-x)); }
__device__ __forceinline__ float tanh_(float x) {
    return 1.f - 2.f * fast_rcp(1.f + __expf(2.f * x));   // saturates correctly
}
__device__ __forceinline__ float hadd(v2f v) { return v.x + v.y; }
__device__ __forceinline__ short bf16rne(float f) {      // fp32 -> bf16 RNE
    unsigned u = __float_as_uint(f);
    u += 0x7FFF + ((u >> 16) & 1);
    return (short)(u >> 16);
}

// d_out is poisoned before every launch: init every element to the combined
// FC bias b_comb = fc3_w @ fc1_b + fc3_b (fc1->fc3 is affine-affine; dropout
// is identity in eval). The scan kernel atomicAdds partial dots on top.
__global__ void init_out_kernel(float* __restrict__ out,
                                const float* __restrict__ fc1_b,
                                const float* __restrict__ fc3_w,
                                const float* __restrict__ fc3_b,
                                int n) {
    int idx = blockIdx.x * blockDim.x + threadIdx.x;
    float b = fc3_b[0];
    #pragma unroll
    for (int k = 0; k < 64; ++k) b += fc3_w[k] * fc1_b[k];
    if (idx < n) out[idx] = b;
}

// One workgroup (128 threads = 2 waves) per BATCH (both directions).
//   wave 0 = CONSUMER: lanes 0-31 forward seq, lanes 32-63 reverse seq.
//            Lane owns ALL FOUR gates (i,f,g,o) of one hidden unit -> the
//            cross-half __shfl_xor (a ~120-cyc ds_swizzle on the recurrence
//            chain) is eliminated; per-step chain = h-bcast ds_read + dot +
//            activations only.
//   wave 1 = PRODUCER: ih projection for BOTH dirs via bf16 MFMA
//            (32 MFMA / 16-step chunk), plus deferred-FC flush + atomicAdd.
// Ring layout (per step-slot, 256 floats): col = d*128 + cidx(gate);
//   cidx: i_k->2k, f_k->2k+1, g_k->64+2k, o_k->64+2k+1, so the consumer
//   reads two b64s: {zi,zf} at d*128+2k and {zg,zo} at d*128+64+2k.
// Bias is seeded in the consumer's hh accumulators (MFMA output is biasless).
// MFMA layouts (guide-verified m89/m118/m120):
//   A (16x32): m=lane&15, k=(lane>>4)*8+j     (8 bf16/lane)
//   B (32x16): n=lane&15, k=(lane>>4)*8+j
//   D (16x16): m=(lane>>4)*4+reg, n=lane&15   (4 fp32/lane)
// CRITICAL (round-6 lesson): empty asm memory clobber at the end of each
// consumer step pins the hst store->load order across unrolled steps.
__global__ void __launch_bounds__(128, 1) lstm_pc_kernel(
    const float* __restrict__ x,
    const float* __restrict__ w_ih_f, const float* __restrict__ w_hh_f,
    const float* __restrict__ b_ih_f, const float* __restrict__ b_hh_f,
    const float* __restrict__ w_ih_r, const float* __restrict__ w_hh_r,
    const float* __restrict__ b_ih_r, const float* __restrict__ b_hh_r,
    const float* __restrict__ fc1_w, const float* __restrict__ fc3_w,
    float* __restrict__ out)
{
    __shared__ float ringF[RSLOT * 256];        // 32 KB: per-step gate projections
    __shared__ float hbuf[2][HH][65];           // 16.6 KB: deferred FC partials
    __shared__ __align__(16) float hst[64];     // 256 B: h(t-1) stage, both dirs

    const int tid  = threadIdx.x;
    const int lane = tid & 63;
    const int wave = tid >> 6;            // 0 consumer, 1 producer
    const int b    = blockIdx.x;
    float* outb = out + (size_t)b * TT;

    if (wave == 1) {
        // ================= PRODUCER (MFMA ih projection, both dirs) =========
        const float* xb = x + (size_t)b * TT * II;
        const int nl = lane & 15;         // A: m / B: n / D: n
        const int q  = lane >> 4;         // quad 0..3
        const float* wih[2] = {w_ih_f, w_ih_r};

        // B fragments (persistent): Bf[d][nt][kf], n = nt*16+nl, k = kf*32+q*8+j
        v8s Bf[2][8][2];
        #pragma unroll
        for (int d = 0; d < 2; ++d)
            #pragma unroll
            for (int nt = 0; nt < 8; ++nt) {
                const int n = nt * 16 + nl;
                #pragma unroll
                for (int kf = 0; kf < 2; ++kf)
                    #pragma unroll
                    for (int j = 0; j < 8; ++j) {
                        const int k = kf * 32 + q * 8 + j;
                        Bf[d][nt][kf][j] = (k < II) ? bf16rne(wih[d][n * II + k])
                                                    : (short)0;
                    }
            }

        // gate g -> interleaved ring column
        auto cidx = [](int g) -> int {
            return (g < 32) ? 2 * g
                 : (g < 64) ? 2 * (g - 32) + 1
                 : (g < 96) ? 64 + 2 * (g - 64)
                            : 64 + 2 * (g - 96) + 1;
        };

        // produce chunk c for both dirs: fills ring slots c*CH .. c*CH+15
        auto produce_chunk = [&](int c) {
            #pragma unroll
            for (int d = 0; d < 2; ++d) {
                const int S = c * CH + nl;             // this lane's A-row step
                const int t = d ? (TT - 1 - S) : S;
                const float* xr = xb + (size_t)t * II;
                v8s A0, A1;
                #pragma unroll
                for (int j = 0; j < 8; ++j) A0[j] = bf16rne(xr[q * 8 + j]);
                #pragma unroll
                for (int j = 0; j < 8; ++j) {
                    const int k = 32 + q * 8 + j;
                    A1[j] = (k < II) ? bf16rne(xr[k]) : (short)0;
                }
                #pragma unroll
                for (int nt = 0; nt < 8; ++nt) {
                    v4f acc = {0.f, 0.f, 0.f, 0.f};
                    acc = __builtin_amdgcn_mfma_f32_16x16x32_bf16(A0, Bf[d][nt][0], acc, 0, 0, 0);
                    acc = __builtin_amdgcn_mfma_f32_16x16x32_bf16(A1, Bf[d][nt][1], acc, 0, 0, 0);
                    const int col = d * 128 + cidx(nt * 16 + nl);
                    #pragma unroll
                    for (int r = 0; r < 4; ++r) {
                        const int slot = (c * CH + q * 4 + r) & (RSLOT - 1);
                        ringF[slot * 256 + col] = acc[r];
                    }
                }
            }
        };
        // flush chunk m: 16 outputs per dir; lanes 0..31 (d = lane>>4)
        auto flush = [&](int m) {
            if (lane < 32) {
                const int d   = lane >> 4;
                const int idx = lane & 15;
                const int ti  = m * CH + idx;
                const int col = ti & 63;
                float d0 = 0.f, d1 = 0.f, d2 = 0.f, d3 = 0.f;
                #pragma unroll
                for (int k = 0; k < HH; k += 4) {
                    d0 += hbuf[d][k    ][col];
                    d1 += hbuf[d][k + 1][col];
                    d2 += hbuf[d][k + 2][col];
                    d3 += hbuf[d][k + 3][col];
                }
                const int t = d ? (TT - 1 - ti) : ti;
                atomicAdd(&outb[t], (d0 + d1) + (d2 + d3));
            }
        };

        produce_chunk(0);
        __syncthreads();
        for (int n = 0; n < NCH; ++n) {
            if (n + 1 < NCH) produce_chunk(n + 1);
            if (n >= 1) flush(n - 1);
            __syncthreads();
        }
        flush(NCH - 1);
    } else {
        // ================= CONSUMER (fp32 recurrence, 2 seqs) ==============
        const int d = lane >> 5;          // 0 fwd (lanes 0-31), 1 rev
        const int k = lane & 31;          // hidden unit
        const float* w_hh = d ? w_hh_r : w_hh_f;
        const float* bi   = d ? b_ih_r : b_ih_f;
        const float* bh   = d ? b_hh_r : b_hh_f;

        // K-packed weight pairs for all 4 gate rows of unit k:
        // wp[D][j] = {w_hh[D*32+k][2j], w_hh[D*32+k][2j+1]}, D = i,f,g,o
        v2f wp[4][16];
        float bb[4];
        #pragma unroll
        for (int D = 0; D < 4; ++D) {
            const int row = D * 32 + k;
            #pragma unroll
            for (int j = 0; j < 16; ++j) {
                wp[D][j].x = w_hh[row * HH + 2 * j];
                wp[D][j].y = w_hh[row * HH + 2 * j + 1];
            }
            bb[D] = bi[row] + bh[row];
        }

        // fused FC weight for hidden unit j = d*32 + k
        float wc = 0.f;
        {
            const int j = d * HH + k;
            #pragma unroll
            for (int n = 0; n < 64; ++n) wc += fc3_w[n] * fc1_w[n * 64 + j];
        }

        hst[lane] = 0.f;                  // h(-1) = 0 (same-wave in-order DS)
        float c = 0.f;

        __syncthreads();                  // matches producer's prologue barrier

        for (int n = 0; n < NCH; ++n) {
            const int slot0 = (n & 1) * CH;
            const int col0  = (n & 3) * CH;
            #pragma unroll
            for (int u = 0; u < CH; ++u) {
                // x-projection pairs (off-chain: issued at step top, used late)
                const float* rp = &ringF[(slot0 + u) * 256 + d * 128 + 2 * k];
                const v2f xz1 = *(const v2f*)rp;          // {px_i, px_f}
                const v2f xz2 = *(const v2f*)(rp + 64);   // {px_g, px_o}

                // h(t-1) broadcast for this dir: 8x b128 (2 addrs/wave = free)
                float4 h4[8];
                #pragma unroll
                for (int j = 0; j < 8; ++j)
                    h4[j] = *(const float4*)&hst[d * 32 + 4 * j];

                v2f aA[4], aB[4];
                #pragma unroll
                for (int D = 0; D < 4; ++D) {
                    aA[D] = (v2f){bb[D], 0.f};            // bias seeded here
                    aB[D] = (v2f){0.f, 0.f};
                }
                #pragma unroll
                for (int j = 0; j < 8; ++j) {
                    v2f p0 = {h4[j].x, h4[j].y};          // adjacent regs, free
                    v2f p1 = {h4[j].z, h4[j].w};
                    #pragma unroll
                    for (int D = 0; D < 4; ++D) {
                        aA[D] = __builtin_elementwise_fma(p0, wp[D][2 * j    ], aA[D]);
                        aB[D] = __builtin_elementwise_fma(p1, wp[D][2 * j + 1], aB[D]);
                    }
                }
                const float zi = xz1.x + hadd(aA[0] + aB[0]);
                const float zf = xz1.y + hadd(aA[1] + aB[1]);
                const float zg = xz2.x + hadd(aA[2] + aB[2]);
                const float zo = xz2.y + hadd(aA[3] + aB[3]);

                // all 4 gates in-lane: no cross-lane op on the chain
                const float gi = sigm(zi);
                const float gf = sigm(zf);
                const float gg = tanh_(zg);
                const float go = sigm(zo);

                c = fmaf(gf, c, gi * gg);
                const float h = go * tanh_(c);

                hst[lane] = h;                        // next step's broadcast
                hbuf[d][k][col0 + u] = h * wc;        // deferred FC
                // ordering fence: store(u) may not sink, loads(u+1) may not
                // hoist. Zero instructions emitted.
                asm volatile("" ::: "memory");
            }
            __syncthreads();
        }
    }
}

extern "C" void kernel_launch(void* const* d_in, const int* in_sizes, int n_in,
                              void* d_out, int out_size, void* d_ws, size_t ws_size,
                              hipStream_t stream) {
    const float* x      = (const float*)d_in[0];
    const float* w_ih_f = (const float*)d_in[1];
    const float* w_hh_f = (const float*)d_in[2];
    const float* b_ih_f = (const float*)d_in[3];
    const float* b_hh_f = (const float*)d_in[4];
    const float* w_ih_r = (const float*)d_in[5];
    const float* w_hh_r = (const float*)d_in[6];
    const float* b_ih_r = (const float*)d_in[7];
    const float* b_hh_r = (const float*)d_in[8];
    const float* fc1_w  = (const float*)d_in[9];
    const float* fc1_b  = (const float*)d_in[10];
    const float* fc3_w  = (const float*)d_in[11];
    const float* fc3_b  = (const float*)d_in[12];
    float* out = (float*)d_out;

    const int n = BB * TT;
    init_out_kernel<<<(n + 255) / 256, 256, 0, stream>>>(out, fc1_b, fc3_w, fc3_b, n);

    // 512 workgroups = batches; 2 waves each (consumer handles both dirs).
    lstm_pc_kernel<<<BB, 128, 0, stream>>>(
        x, w_ih_f, w_hh_f, b_ih_f, b_hh_f,
        w_ih_r, w_hh_r, b_ih_r, b_hh_r,
        fc1_w, fc3_w, out);
}